// Round 4
// baseline (446.630 us; speedup 1.0000x reference)
//
#include <hip/hip_runtime.h>
#include <hip/hip_bf16.h>

#define B_ 2048
#define T_ 64
#define H_ 256
#define V_ 51
#define Z_ 32
#define K_ 1000

typedef __bf16 bf16x8 __attribute__((ext_vector_type(8)));
typedef float floatx4 __attribute__((ext_vector_type(4)));

__device__ inline unsigned short f2bf(float f){
    unsigned int u = __float_as_uint(f);
    u += 0x7fffu + ((u >> 16) & 1u);
    return (unsigned short)(u >> 16);
}
__device__ inline float sigm(float x){
    float e = __expf(-x);
    return __builtin_amdgcn_rcpf(1.0f + e);
}
// tanh(x) = 2/(1+e^{-2x}) - 1   (sign-correct; saturates to +/-1)
__device__ inline float tanh_fast(float x){
    float e = __expf(-2.0f*x);
    return __builtin_fmaf(2.0f, __builtin_amdgcn_rcpf(1.0f + e), -1.0f);
}
__device__ inline float permlane_merge(float d, float s){
    asm volatile("v_permlane32_swap_b32 %0, %1" : "+v"(d), "+v"(s));
    return d;
}
__device__ inline float lo16(unsigned int u){ return __uint_as_float(u << 16); }
__device__ inline float hi16(unsigned int u){ return __uint_as_float(u & 0xffff0000u); }

// ---------------- fused prep kernel ----------------
// region A: packed gate tables (enc+dec), region B: pack w_hh frags, region C: pack w_out frags
__global__ __launch_bounds__(256) void k_prep(
    const float* __restrict__ enc_emb, const float* __restrict__ enc_wih, const float* __restrict__ enc_bih,
    const float* __restrict__ enc_bhh,
    const float* __restrict__ dec_emb, const float* __restrict__ dec_wih, const float* __restrict__ dec_bih,
    const float* __restrict__ dec_bhh,
    const float* __restrict__ whh_e, const float* __restrict__ whh_d, const float* __restrict__ w_out,
    unsigned short* __restrict__ tep, unsigned short* __restrict__ tdp,
    unsigned short* __restrict__ bpe, unsigned short* __restrict__ bpd,
    unsigned short* __restrict__ bpo)
{
    int id = blockIdx.x*256 + threadIdx.x;
    if (id < 2*V_*768){
        int which = id / (V_*768), r = id % (V_*768);
        int v = r / 768, g = r % 768;
        int gate = g >> 8, col = g & 255;
        float s;
        if (!which){
            s = enc_bih[g] + (gate < 2 ? enc_bhh[g] : 0.0f);
            for (int e=0;e<64;++e) s += enc_emb[v*64+e]*enc_wih[g*64+e];
            tep[(v*256+col)*4 + gate] = f2bf(s);
        } else {
            s = dec_bih[g] + (gate < 2 ? dec_bhh[g] : 0.0f);
            for (int e=0;e<64;++e) s += dec_emb[v*64+e]*dec_wih[g*128+64+e];
            tdp[(v*256+col)*4 + gate] = f2bf(s);
        }
    } else if (id < 78336 + 2*196608){
        int rid = id - 78336;
        int which = rid / 196608, e = rid % 196608;
        int j = e & 7, lane = (e>>3)&63, kt = (e>>9)&7, nt = e>>12;
        int k = kt*32 + (lane>>4)*8 + j, n = nt*16 + (lane&15);
        const float* wmat = which ? whh_d : whh_e;
        (which ? bpd : bpe)[e] = f2bf(wmat[n*256+k]);
    } else if (id < 78336 + 2*196608 + 16384){
        int cid = id - (78336 + 2*196608);
        int j = cid & 7, lane = (cid>>3)&63, kt = (cid>>9)&7, nt = cid>>12;
        int k = kt*32 + (lane>>4)*8 + j, n = nt*16 + (lane&15);
        bpo[cid] = f2bf(n < V_ ? w_out[n*256+k] : 0.0f);
    }
}

// ---------------- GRU recurrence: 256 blocks x 8 batch rows, 8 waves ----------------
template<int DEC>
__global__ __launch_bounds__(512, 2) void k_gru(
    const int* __restrict__ x, const unsigned short* __restrict__ tblg,
    const unsigned short* __restrict__ bpack, const float* __restrict__ bhh,
    const float* __restrict__ h0, const unsigned short* __restrict__ zvp,
    float* __restrict__ h_last, unsigned short* __restrict__ outs)
{
    const int Tn = DEC ? (T_-1) : T_;
    __shared__ alignas(16) unsigned short tbl[V_*1024];        // [v][col][4] bf16
    __shared__ alignas(16) unsigned short hbuf[2*4096];        // [buf][16 rows][256] bf16, swizzled
    __shared__ alignas(16) unsigned short zvs[DEC ? 8192 : 8]; // [row][col][4] bf16
    __shared__ unsigned int tpk[T_][2];

    const int tid = threadIdx.x;
    const int w = tid>>6, lane = tid&63, lr = lane&15, lp = lane>>4;
    const int b0 = blockIdx.x*8;
    const int jm = w + ((lane>=32)?8:0);
    const int col_m = jm*16 + lr;
    const int rbase = (lp&1)*4;
    const int colm4 = col_m*4;

    // ---- weight fragments resident (192 regs across arch+acc file) ----
    const bf16x8* bp = (const bf16x8*)bpack;
    bf16x8 wf[2][3][8];
    #pragma unroll
    for (int ji=0; ji<2; ++ji)
      #pragma unroll
      for (int g=0; g<3; ++g)
        #pragma unroll
        for (int kt=0; kt<8; ++kt)
            wf[ji][g][kt] = bp[(((g*16) + w + 8*ji)*8 + kt)*64 + lane];

    // ---- stage tables into LDS ----
    {
        uint4* d4 = (uint4*)tbl; const uint4* s4 = (const uint4*)tblg;
        for (int i=tid; i<(V_*1024)/8; i+=512) d4[i] = s4[i];
    }
    if (DEC){
        uint4* d4 = (uint4*)zvs; const uint4* s4 = (const uint4*)(zvp + (size_t)b0*1024);
        for (int i=tid; i<1024; i+=512) d4[i] = s4[i];
    }
    for (int i=tid; i<4096; i+=512){
        int bufi = i>>11, rr = 8 + ((i>>8)&7), c = i&255;
        hbuf[bufi*4096 + rr*256 + c] = 0;
    }
    if (tid < 128){
        int t = tid>>1, g = tid&1;
        unsigned int p = 0;
        #pragma unroll
        for (int r=0;r<4;++r) p |= ((unsigned int)x[(size_t)(b0 + g*4 + r)*T_ + t]) << (8*r);
        tpk[t][g] = p;
    }

    // ---- per-lane state ----
    const float bhn = bhh[2*H_ + col_m];
    float hreg[4];
    int waddr[4];
    #pragma unroll
    for (int q=0; q<4; ++q){
        int row = rbase + q;
        float hv = DEC ? h0[(size_t)(b0+row)*H_ + col_m] : 0.0f;
        hreg[q] = hv;
        waddr[q] = row*256 + (col_m ^ (row<<3));
        hbuf[waddr[q]] = f2bf(hv);
    }
    const int s3 = (lr&7)<<3, lpb = lp*8;
    const int aidx0 = lr*256 + (lpb ^ s3);
    const int aidx1 = lr*256 + ((32 + lpb) ^ s3);
    const int zb = rbase*1024 + colm4;
    const int crow = w, cc4 = lane<<2;
    const int csrc = crow*256 + (cc4 ^ (crow<<3));
    unsigned short* cdst0 = DEC ? (outs + ((size_t)(b0+crow)*(T_-1))*H_ + cc4) : nullptr;
    __syncthreads();

#define LDH(i) (*(const bf16x8*)&hbuf[(cur<<12) + (i)])
#define MFMA_(ji,g,kt,av) acc[ji][g] = __builtin_amdgcn_mfma_f32_16x16x32_bf16(av, wf[ji][g][kt], acc[ji][g], 0,0,0)

    auto step = [&](int t, int cur) {
        const int nxt = cur^1;
        unsigned int tp = tpk[t][lp&1];
        floatx4 acc[2][3] = {};

        // ---- phase 1: r (g=0) and z (g=1) chains, 32 MFMAs ----
        __builtin_amdgcn_s_setprio(1);
        bf16x8 aA = LDH(aidx0), aB = LDH(aidx1), aC = LDH(aidx0 + 64);
        #pragma unroll
        for (int kt=0; kt<8; ++kt){
            bf16x8 av = (kt%3==0) ? aA : ((kt%3==1) ? aB : aC);
            MFMA_(0,0,kt,av); MFMA_(1,0,kt,av);
            MFMA_(0,1,kt,av); MFMA_(1,1,kt,av);
            if (kt+3 < 8){
                int nk = kt+3;
                bf16x8 nv = LDH(((nk&1)?aidx1:aidx0) + ((nk>>1)<<6));
                if (kt%3==0) aA = nv; else if (kt%3==1) aB = nv; else aC = nv;
            }
        }

        // gate-input LDS reads (land during phase 2)
        uint2 tv[4];
        #pragma unroll
        for (int q=0;q<4;++q){
            int tok = (tp >> (8*q)) & 255;
            tv[q] = *(const uint2*)&tbl[(tok<<10) + colm4];
        }
        uint2 zv[4];
        if (DEC){
            #pragma unroll
            for (int q=0;q<4;++q) zv[q] = *(const uint2*)&zvs[zb + q*1024];
        }

        // ---- phase 2: n (g=2) chains, 16 MFMAs, woven with r/z gate VALU ----
        float rm[4], zm[4], rg[4], zg[4];
        bf16x8 c0 = LDH(aidx0), c1 = LDH(aidx1), c2 = LDH(aidx0 + 64);
        MFMA_(0,2,0,c0); MFMA_(1,2,0,c0); c0 = LDH(aidx1 + 64);
        #pragma unroll
        for (int q=0;q<4;++q) rm[q] = permlane_merge(acc[0][0][q], acc[1][0][q]);
        MFMA_(0,2,1,c1); MFMA_(1,2,1,c1); c1 = LDH(aidx0 + 128);
        {
            float xr0 = lo16(tv[0].x), xr1 = lo16(tv[1].x);
            if (DEC){ xr0 += lo16(zv[0].x); xr1 += lo16(zv[1].x); }
            rg[0] = sigm(xr0 + rm[0]); rg[1] = sigm(xr1 + rm[1]);
        }
        MFMA_(0,2,2,c2); MFMA_(1,2,2,c2); c2 = LDH(aidx1 + 128);
        {
            float xr2 = lo16(tv[2].x), xr3 = lo16(tv[3].x);
            if (DEC){ xr2 += lo16(zv[2].x); xr3 += lo16(zv[3].x); }
            rg[2] = sigm(xr2 + rm[2]); rg[3] = sigm(xr3 + rm[3]);
        }
        MFMA_(0,2,3,c0); MFMA_(1,2,3,c0); c0 = LDH(aidx0 + 192);
        #pragma unroll
        for (int q=0;q<4;++q) zm[q] = permlane_merge(acc[0][1][q], acc[1][1][q]);
        MFMA_(0,2,4,c1); MFMA_(1,2,4,c1); c1 = LDH(aidx1 + 192);
        {
            float xz0 = hi16(tv[0].x), xz1 = hi16(tv[1].x);
            if (DEC){ xz0 += hi16(zv[0].x); xz1 += hi16(zv[1].x); }
            zg[0] = sigm(xz0 + zm[0]); zg[1] = sigm(xz1 + zm[1]);
        }
        MFMA_(0,2,5,c2); MFMA_(1,2,5,c2);
        {
            float xz2 = hi16(tv[2].x), xz3 = hi16(tv[3].x);
            if (DEC){ xz2 += hi16(zv[2].x); xz3 += hi16(zv[3].x); }
            zg[2] = sigm(xz2 + zm[2]); zg[3] = sigm(xz3 + zm[3]);
        }
        MFMA_(0,2,6,c0); MFMA_(1,2,6,c0);
        MFMA_(0,2,7,c1); MFMA_(1,2,7,c1);
        __builtin_amdgcn_s_setprio(0);

        // ---- tail: n gate + h update ----
        #pragma unroll
        for (int q=0; q<4; ++q){
            float nm = permlane_merge(acc[0][2][q], acc[1][2][q]);
            float xn = lo16(tv[q].y);
            if (DEC) xn += lo16(zv[q].y);
            float ng = tanh_fast(__builtin_fmaf(rg[q], nm + bhn, xn));
            float hv = __builtin_fmaf(zg[q], hreg[q] - ng, ng);
            hreg[q] = hv;
            hbuf[(nxt<<12) + waddr[q]] = f2bf(hv);
        }
        __syncthreads();
        if (DEC){
            uint2 v = *(const uint2*)&hbuf[(nxt<<12) + csrc];
            *(uint2*)(cdst0 + (size_t)t*H_) = v;
        }
    };

    for (int t=0; t+1<Tn; t+=2){ step(t,0); step(t+1,1); }
    if (Tn & 1) step(Tn-1, 0);

#undef LDH
#undef MFMA_

    if (!DEC){
        #pragma unroll
        for (int q=0; q<4; ++q)
            h_last[(size_t)(b0+rbase+q)*H_ + col_m] = hreg[q];
    }
}

// ---------------- fused latent (mu/logvar/toq, KL, VQ, Q) + mid (hidden, zvp) ----------------
__global__ __launch_bounds__(256) void k_latmid(
    const float* __restrict__ hlast,
    const float* __restrict__ w_mu, const float* __restrict__ b_mu,
    const float* __restrict__ w_std, const float* __restrict__ b_std,
    const float* __restrict__ w_q, const float* __restrict__ b_q,
    const float* __restrict__ cb,
    const float* __restrict__ w_up, const float* __restrict__ b_up,
    const float* __restrict__ dwih,
    float* __restrict__ hidden, unsigned short* __restrict__ zvp,
    float* __restrict__ pKL, float* __restrict__ pQ, float* __restrict__ out_idx)
{
    __shared__ float hs[8][H_];
    __shared__ float mu8[8][Z_], lv8[8][Z_], tq8[8][Z_];
    __shared__ float cbs[256*Z_];
    __shared__ float red[256];
    __shared__ int redi[256];
    __shared__ float zs[8][64];
    const int tid = threadIdx.x;
    const int b0 = blockIdx.x*8;

    for (int i=tid; i<8*H_; i+=256) hs[i>>8][i&255] = hlast[(size_t)(b0+(i>>8))*H_ + (i&255)];
    __syncthreads();

    for (int id=tid; id<768; id+=256){
        int o = id % 96, bb = id / 96;
        int which = o>>5, zi = o&31;
        const float* wm = which==0 ? w_mu : (which==1 ? w_std : w_q);
        const float* bm = which==0 ? b_mu : (which==1 ? b_std : b_q);
        float s = bm[zi];
        const float* h = hs[bb];
        for (int k=0;k<H_;++k) s += h[k]*wm[zi*H_+k];
        if (which==0) mu8[bb][zi]=s; else if (which==1) lv8[bb][zi]=s; else tq8[bb][zi]=s;
    }
    __syncthreads();

    {
        int bb = tid>>5, zi = tid&31;
        float m = mu8[bb][zi], l = lv8[bb][zi];
        red[tid] = 0.5f*(m*m + __expf(l) - l - 1.0f);
    }
    __syncthreads();
    for (int s=128; s>0; s>>=1){ if (tid<s) red[tid]+=red[tid+s]; __syncthreads(); }
    if (tid==0) pKL[blockIdx.x] = red[0];
    __syncthreads();

    const int bb = tid>>5, c = tid&31;
    float best = 3.4e38f; int bi = 0;
    for (int ch=0; ch<4; ++ch){
        int kb = ch*256;
        int kn = (K_ - kb) < 256 ? (K_ - kb) : 256;
        for (int i=tid; i<kn*Z_; i+=256) cbs[i] = cb[(size_t)kb*Z_ + i];
        __syncthreads();
        for (int jj=0; jj<8; ++jj){
            int k = c + 32*(ch*8+jj);
            if (k < K_){
                const float* cv = &cbs[(k-kb)*Z_];
                float d = 0.f;
                #pragma unroll
                for (int ci=0; ci<Z_; ++ci){ float df = tq8[bb][ci]-cv[ci]; d += df*df; }
                if (d < best){ best = d; bi = k; }
            }
        }
        __syncthreads();
    }
    red[tid]=best; redi[tid]=bi;
    __syncthreads();
    for (int s=16; s>0; s>>=1){
        if ((tid&31) < s){
            float ob = red[tid+s]; int oi = redi[tid+s];
            if (ob < red[tid] || (ob == red[tid] && oi < redi[tid])){ red[tid]=ob; redi[tid]=oi; }
        }
        __syncthreads();
    }
    if (tid < 8){
        int k = redi[tid*32];
        float s = 0.f;
        for (int ci=0; ci<Z_; ++ci){ float df = cb[(size_t)k*Z_+ci]-tq8[tid][ci]; s += df*df; }
        red[tid] = s * (0.3f/32.0f);
        out_idx[b0+tid] = (float)k;
    }
    __syncthreads();
    if (tid==0){ float q=0; for (int i=0;i<8;++i) q+=red[i]; pQ[blockIdx.x]=q; }
    for (int i=tid; i<8*64; i+=256){
        int bb2 = i>>6, cc = i&63;
        int k = redi[bb2*32];
        zs[bb2][cc] = (cc < Z_) ? cb[(size_t)k*Z_+cc] : mu8[bb2][cc-Z_];
    }
    __syncthreads();

    // mid: hidden = zcat@w_up.T + b_up ; zvp = packed bf16 zcat@dec_wih[:, :64].T
    for (int id=tid; id<8*1024; id+=256){
        int bb2 = id>>10, o = id&1023;
        const float* zr = zs[bb2];
        if (o < H_){
            float s = b_up[o];
            const float* wr = w_up + o*64;
            for (int ck=0;ck<64;++ck) s += zr[ck]*wr[ck];
            hidden[(size_t)(b0+bb2)*H_ + o] = s;
        } else {
            int g = o - H_;
            int gate = g>>8, col = g&255;
            float s = 0.f;
            const float* wr = dwih + (size_t)g*128;
            for (int ck=0;ck<64;++ck) s += zr[ck]*wr[ck];
            zvp[((size_t)(b0+bb2)*256 + col)*4 + gate] = f2bf(s);
        }
    }
}

// ---------------- logits + log_softmax + loss ----------------
__global__ __launch_bounds__(256) void k_loss(
    const unsigned short* __restrict__ outs, const unsigned short* __restrict__ bpo,
    const float* __restrict__ b_out, const int* __restrict__ x,
    float* __restrict__ pred, float* __restrict__ pXL, float* __restrict__ pNP)
{
    __shared__ float ll[16][64];
    __shared__ float bo[64];
    __shared__ float redf[256], redn[256];
    const int tid = threadIdx.x, w = tid>>6, lane = tid&63, lr = lane&15, lp = lane>>4;
    const bf16x8* bpofr = (const bf16x8*)bpo;
    bf16x8 bw[8];
    #pragma unroll
    for (int kt=0;kt<8;++kt) bw[kt] = bpofr[(w*8+kt)*64 + lane];
    if (tid < 64) bo[tid] = (tid < V_) ? b_out[tid] : 0.0f;
    float xl = 0.f, npn = 0.f;
    const int row = tid>>4, vl = tid&15;
    for (int cc=0; cc<4; ++cc){
        int row0 = (blockIdx.x*4 + cc)*16;
        floatx4 acc = {0,0,0,0};
        #pragma unroll
        for (int kt=0;kt<8;++kt){
            bf16x8 av = *(const bf16x8*)&outs[(size_t)(row0+lr)*H_ + kt*32 + lp*8];
            acc = __builtin_amdgcn_mfma_f32_16x16x32_bf16(av, bw[kt], acc, 0,0,0);
        }
        __syncthreads();
        #pragma unroll
        for (int q=0;q<4;++q) ll[lp*4+q][w*16+lr] = acc[q];
        __syncthreads();
        float lv[4];
        #pragma unroll
        for (int k2=0;k2<4;++k2){
            int v = vl + 16*k2;
            lv[k2] = (v < V_) ? ll[row][v] + bo[v] : -3.4e38f;
        }
        float m = lv[0]; int am = vl;
        #pragma unroll
        for (int k2=1;k2<4;++k2){ if (lv[k2] > m){ m = lv[k2]; am = vl + 16*k2; } }
        #pragma unroll
        for (int off=1; off<16; off<<=1){
            float om = __shfl_xor(m, off, 16);
            int oa = __shfl_xor(am, off, 16);
            if (om > m || (om == m && oa < am)){ m = om; am = oa; }
        }
        float se = 0.f;
        #pragma unroll
        for (int k2=0;k2<4;++k2) se += __expf(lv[k2]-m);
        #pragma unroll
        for (int off=1; off<16; off<<=1) se += __shfl_xor(se, off, 16);
        if (vl == 0){
            int rowg = row0 + row;
            int b = rowg/63, tt = rowg - b*63;
            int tgt = x[(size_t)b*T_ + tt + 1];
            pred[rowg] = (float)am;
            if (tgt != 0){
                float lse = m + __logf(se);
                xl += ll[row][tgt] + bo[tgt] - lse;
                npn += 1.f;
            }
        }
    }
    redf[tid]=xl; redn[tid]=npn;
    __syncthreads();
    for (int s=128;s>0;s>>=1){ if (tid<s){ redf[tid]+=redf[tid+s]; redn[tid]+=redn[tid+s]; } __syncthreads(); }
    if (tid==0){ pXL[blockIdx.x]=redf[0]; pNP[blockIdx.x]=redn[0]; }
}

// ---------------- final reduce ----------------
__global__ __launch_bounds__(256) void k_reduce(
    const float* __restrict__ pKL, const float* __restrict__ pQ,
    const float* __restrict__ pXL, const float* __restrict__ pNP, float* __restrict__ dout)
{
    __shared__ float r[256];
    const int tid = threadIdx.x;
    r[tid] = pKL[tid]; __syncthreads();
    for (int s=128;s>0;s>>=1){ if (tid<s) r[tid]+=r[tid+s]; __syncthreads(); }
    if (tid==0) dout[129026] = r[0];
    __syncthreads();
    r[tid] = pQ[tid]; __syncthreads();
    for (int s=128;s>0;s>>=1){ if (tid<s) r[tid]+=r[tid+s]; __syncthreads(); }
    if (tid==0) dout[129027] = r[0];
    __syncthreads();
    float a = 0.f;
    for (int i=tid;i<2016;i+=256) a += pXL[i];
    r[tid] = a; __syncthreads();
    for (int s=128;s>0;s>>=1){ if (tid<s) r[tid]+=r[tid+s]; __syncthreads(); }
    if (tid==0) dout[0] = -r[0];
    __syncthreads();
    a = 0.f;
    for (int i=tid;i<2016;i+=256) a += pNP[i];
    r[tid] = a; __syncthreads();
    for (int s=128;s>0;s>>=1){ if (tid<s) r[tid]+=r[tid+s]; __syncthreads(); }
    if (tid==0) dout[1] = r[0];
}

extern "C" void kernel_launch(void* const* d_in, const int* in_sizes, int n_in,
                              void* d_out, int out_size, void* d_ws, size_t ws_size,
                              hipStream_t stream)
{
    const int*   x       = (const int*)  d_in[0];
    const float* enc_emb = (const float*)d_in[1];
    const float* enc_wih = (const float*)d_in[2];
    const float* enc_whh = (const float*)d_in[3];
    const float* enc_bih = (const float*)d_in[4];
    const float* enc_bhh = (const float*)d_in[5];
    const float* w_mu    = (const float*)d_in[6];
    const float* b_mu    = (const float*)d_in[7];
    const float* w_std   = (const float*)d_in[8];
    const float* b_std   = (const float*)d_in[9];
    const float* w_q     = (const float*)d_in[10];
    const float* b_q     = (const float*)d_in[11];
    const float* w_up    = (const float*)d_in[12];
    const float* b_up    = (const float*)d_in[13];
    const float* cb      = (const float*)d_in[14];
    const float* dec_emb = (const float*)d_in[15];
    const float* dec_wih = (const float*)d_in[16];
    const float* dec_whh = (const float*)d_in[17];
    const float* dec_bih = (const float*)d_in[18];
    const float* dec_bhh = (const float*)d_in[19];
    const float* w_out   = (const float*)d_in[20];
    const float* b_out   = (const float*)d_in[21];

    float* ws = (float*)d_ws;
    unsigned short* tep = (unsigned short*)(ws + 0);        // 52224 ush
    unsigned short* tdp = (unsigned short*)(ws + 26112);    // 52224 ush
    unsigned short* bpe = (unsigned short*)(ws + 52224);    // 196608 ush
    unsigned short* bpd = (unsigned short*)(ws + 150528);   // 196608 ush
    unsigned short* bpo = (unsigned short*)(ws + 248832);   // 16384 ush
    float* hl   = ws + 257024;    // 524288
    float* hid  = ws + 912384;    // 524288
    unsigned short* zvp  = (unsigned short*)(ws + 1436672); // 2097152 ush
    unsigned short* outs = (unsigned short*)(ws + 2485248); // 33030144 ush
    float* pKL  = ws + 19000320;  // 256
    float* pQ   = ws + 19000576;  // 256
    float* pXL  = ws + 19000832;  // 2016
    float* pNP  = ws + 19002848;  // 2016

    float* dout = (float*)d_out;

    k_prep<<<1906,256,0,stream>>>(enc_emb, enc_wih, enc_bih, enc_bhh,
                                  dec_emb, dec_wih, dec_bih, dec_bhh,
                                  enc_whh, dec_whh, w_out,
                                  tep, tdp, bpe, bpd, bpo);
    k_gru<0><<<256,512,0,stream>>>(x, tep, bpe, enc_bhh, nullptr, nullptr, hl, nullptr);
    k_latmid<<<256,256,0,stream>>>(hl, w_mu,b_mu,w_std,b_std,w_q,b_q, cb,
                                   w_up, b_up, dec_wih, hid, zvp, pKL, pQ, dout + 129028);
    k_gru<1><<<256,512,0,stream>>>(x, tdp, bpd, dec_bhh, hid, zvp, nullptr, outs);
    k_loss<<<2016,256,0,stream>>>(outs, bpo, b_out, x, dout + 2, pXL, pNP);
    k_reduce<<<1,256,0,stream>>>(pKL, pQ, pXL, pNP, dout);
}

// Round 5
// 331.832 us; speedup vs baseline: 1.3460x; 1.3460x over previous
//
#include <hip/hip_runtime.h>
#include <hip/hip_bf16.h>

#define B_ 2048
#define T_ 64
#define H_ 256
#define V_ 51
#define Z_ 32
#define K_ 1000
#define LOG2E 1.4426950408889634f

typedef __bf16 bf16x8 __attribute__((ext_vector_type(8)));
typedef float floatx4 __attribute__((ext_vector_type(4)));

__device__ inline unsigned short f2bf(float f){
    unsigned int u = __float_as_uint(f);
    u += 0x7fffu + ((u >> 16) & 1u);
    return (unsigned short)(u >> 16);
}
// sigmoid with pre-scaled input: x = log2e * (raw). sigm = 1/(1+2^-x)
__device__ inline float sigm2(float x){
    float e; asm("v_exp_f32 %0, -%1" : "=v"(e) : "v"(x));
    return __builtin_amdgcn_rcpf(1.0f + e);
}
// tanh(y), y unscaled: t = 2^(-2*log2e*y); tanh = 2/(1+t) - 1
__device__ inline float tanh2(float y){
    float t = y * (-2.0f*LOG2E);
    float e; asm("v_exp_f32 %0, %1" : "=v"(e) : "v"(t));
    return __builtin_fmaf(2.0f, __builtin_amdgcn_rcpf(1.0f + e), -1.0f);
}
__device__ inline float permlane_merge(float d, float s){
    asm("v_permlane32_swap_b32 %0, %1" : "+v"(d), "+v"(s));
    return d;
}
__device__ inline float lo16(unsigned int u){ return __uint_as_float(u << 16); }
__device__ inline float hi16(unsigned int u){ return __uint_as_float(u & 0xffff0000u); }

// ---------------- fused prep kernel ----------------
// A: packed gate tables (enc+dec) [r,z pre-scaled by log2e]; B: pack w_hh frags [r,z scaled]; C: pack w_out frags
__global__ __launch_bounds__(256) void k_prep(
    const float* __restrict__ enc_emb, const float* __restrict__ enc_wih, const float* __restrict__ enc_bih,
    const float* __restrict__ enc_bhh,
    const float* __restrict__ dec_emb, const float* __restrict__ dec_wih, const float* __restrict__ dec_bih,
    const float* __restrict__ dec_bhh,
    const float* __restrict__ whh_e, const float* __restrict__ whh_d, const float* __restrict__ w_out,
    unsigned short* __restrict__ tep, unsigned short* __restrict__ tdp,
    unsigned short* __restrict__ bpe, unsigned short* __restrict__ bpd,
    unsigned short* __restrict__ bpo)
{
    int id = blockIdx.x*256 + threadIdx.x;
    if (id < 2*V_*768){
        int which = id / (V_*768), r = id % (V_*768);
        int v = r / 768, g = r % 768;
        int gate = g >> 8, col = g & 255;
        float s;
        if (!which){
            s = enc_bih[g] + (gate < 2 ? enc_bhh[g] : 0.0f);
            for (int e=0;e<64;++e) s += enc_emb[v*64+e]*enc_wih[g*64+e];
            if (gate < 2) s *= LOG2E;
            tep[(v*256+col)*4 + gate] = f2bf(s);
        } else {
            s = dec_bih[g] + (gate < 2 ? dec_bhh[g] : 0.0f);
            for (int e=0;e<64;++e) s += dec_emb[v*64+e]*dec_wih[g*128+64+e];
            if (gate < 2) s *= LOG2E;
            tdp[(v*256+col)*4 + gate] = f2bf(s);
        }
    } else if (id < 78336 + 2*196608){
        int rid = id - 78336;
        int which = rid / 196608, e = rid % 196608;
        int j = e & 7, lane = (e>>3)&63, kt = (e>>9)&7, nt = e>>12;
        int k = kt*32 + (lane>>4)*8 + j, n = nt*16 + (lane&15);
        const float* wmat = which ? whh_d : whh_e;
        float wv = wmat[n*256+k];
        if (nt < 32) wv *= LOG2E;     // r,z gate rows pre-scaled
        (which ? bpd : bpe)[e] = f2bf(wv);
    } else if (id < 78336 + 2*196608 + 16384){
        int cid = id - (78336 + 2*196608);
        int j = cid & 7, lane = (cid>>3)&63, kt = (cid>>9)&7, nt = cid>>12;
        int k = kt*32 + (lane>>4)*8 + j, n = nt*16 + (lane&15);
        bpo[cid] = f2bf(n < V_ ? w_out[n*256+k] : 0.0f);
    }
}

// ---------------- GRU recurrence: 256 blocks x 8 batch rows, 8 waves ----------------
// __launch_bounds__(512, 2): 2 waves/EU -> weights stay AGPR-resident (round-3 proven).
template<int DEC>
__global__ __launch_bounds__(512, 2) void k_gru(
    const int* __restrict__ x, const unsigned short* __restrict__ tblg,
    const unsigned short* __restrict__ bpack, const float* __restrict__ bhh,
    const float* __restrict__ h0, const unsigned short* __restrict__ zvp,
    float* __restrict__ h_last, unsigned short* __restrict__ outs)
{
    const int Tn = DEC ? (T_-1) : T_;
    __shared__ alignas(16) unsigned short tbl[V_*1024];   // [v][col][4] bf16
    __shared__ alignas(16) unsigned short hbuf[2*4096];   // [buf][16 rows][256] bf16, swizzled
    __shared__ unsigned int tpk[T_][2];

    const int tid = threadIdx.x;
    const int w = tid>>6, lane = tid&63, lr = lane&15, lp = lane>>4;
    const int b0 = blockIdx.x*8;
    const int jm = w + ((lane>=32)?8:0);
    const int col_m = jm*16 + lr;
    const int rbase = (lp&1)*4;
    const int colm4 = col_m*4;

    // ---- weight fragments resident (AGPR file) ----
    const bf16x8* bp = (const bf16x8*)bpack;
    bf16x8 wf[2][3][8];
    #pragma unroll
    for (int ji=0; ji<2; ++ji)
      #pragma unroll
      for (int g=0; g<3; ++g)
        #pragma unroll
        for (int kt=0; kt<8; ++kt)
            wf[ji][g][kt] = bp[(((g*16) + w + 8*ji)*8 + kt)*64 + lane];

    // ---- stage table into LDS ----
    {
        uint4* d4 = (uint4*)tbl; const uint4* s4 = (const uint4*)tblg;
        for (int i=tid; i<(V_*1024)/8; i+=512) d4[i] = s4[i];
    }
    for (int i=tid; i<4096; i+=512){
        int bufi = i>>11, rr = 8 + ((i>>8)&7), c = i&255;
        hbuf[bufi*4096 + rr*256 + c] = 0;
    }
    if (tid < 128){
        int t = tid>>1, g = tid&1;
        unsigned int p = 0;
        #pragma unroll
        for (int r=0;r<4;++r) p |= ((unsigned int)x[(size_t)(b0 + g*4 + r)*T_ + t]) << (8*r);
        tpk[t][g] = p;
    }

    // ---- per-lane state ----
    const float bhn = bhh[2*H_ + col_m];
    float hreg[4];
    int waddr[4];
    #pragma unroll
    for (int q=0; q<4; ++q){
        int row = rbase + q;
        float hv = DEC ? h0[(size_t)(b0+row)*H_ + col_m] : 0.0f;
        hreg[q] = hv;
        waddr[q] = row*256 + (col_m ^ (row<<3));
        hbuf[waddr[q]] = f2bf(hv);
    }
    // DEC: z-projection contribution is t-invariant -> hoist to registers (r,z pre-scaled)
    float zr_[4], zz_[4], zn_[4];
    if (DEC){
        #pragma unroll
        for (int q=0; q<4; ++q){
            const unsigned short* zp = zvp + (((size_t)(b0+rbase+q))*256 + col_m)*4;
            uint2 zv = *(const uint2*)zp;
            zr_[q] = lo16(zv.x); zz_[q] = hi16(zv.x); zn_[q] = lo16(zv.y);
        }
    }
    const int s3 = (lr&7)<<3, lpb = lp*8;
    const int aidx0 = lr*256 + (lpb ^ s3);
    const int aidx1 = lr*256 + ((32 + lpb) ^ s3);
    const int crow = w, cc4 = lane<<2;
    const int csrc = crow*256 + (cc4 ^ (crow<<3));
    unsigned short* cdst0 = DEC ? (outs + ((size_t)(b0+crow)*(T_-1))*H_ + cc4) : nullptr;
    __syncthreads();

#define LDH(i) (*(const bf16x8*)&hbuf[(cur<<12) + (i)])
#define MFMA_(ji,g,kt,av) acc[ji][g] = __builtin_amdgcn_mfma_f32_16x16x32_bf16(av, wf[ji][g][kt], acc[ji][g], 0,0,0)

    auto step = [&](int t, int cur) {
        const int nxt = cur^1;
        unsigned int tp = tpk[t][lp&1];
        floatx4 acc[2][3] = {};

        // ---- phase 1: r (g=0) and z (g=1) chains, 32 MFMAs ----
        {
            bf16x8 aA = LDH(aidx0), aB = LDH(aidx1), aC = LDH(aidx0 + 64);
            #pragma unroll
            for (int kt=0; kt<8; ++kt){
                bf16x8 av = (kt%3==0) ? aA : ((kt%3==1) ? aB : aC);
                MFMA_(0,0,kt,av); MFMA_(1,0,kt,av);
                MFMA_(0,1,kt,av); MFMA_(1,1,kt,av);
                if (kt+3 < 8){
                    int nk = kt+3;
                    bf16x8 nv = LDH(((nk&1)?aidx1:aidx0) + ((nk>>1)<<6));
                    if (kt%3==0) aA = nv; else if (kt%3==1) aB = nv; else aC = nv;
                }
            }
        }
        // gate-input LDS reads (latency hides under phase 2)
        uint2 tv[4];
        #pragma unroll
        for (int q=0;q<4;++q){
            int tok = (tp >> (8*q)) & 255;
            tv[q] = *(const uint2*)&tbl[(tok<<10) + colm4];
        }
        // ---- phase 2: n (g=2) chains, 16 MFMAs ----
        {
            bf16x8 aA = LDH(aidx0), aB = LDH(aidx1), aC = LDH(aidx0 + 64);
            #pragma unroll
            for (int kt=0; kt<8; ++kt){
                bf16x8 av = (kt%3==0) ? aA : ((kt%3==1) ? aB : aC);
                MFMA_(0,2,kt,av); MFMA_(1,2,kt,av);
                if (kt+3 < 8){
                    int nk = kt+3;
                    bf16x8 nv = LDH(((nk&1)?aidx1:aidx0) + ((nk>>1)<<6));
                    if (kt%3==0) aA = nv; else if (kt%3==1) aB = nv; else aC = nv;
                }
            }
        }
        // ---- gate VALU (r,z independent of n-chains; scheduler may sink into their shadow) ----
        float rg[4], zg[4];
        #pragma unroll
        for (int q=0;q<4;++q){
            float rm = permlane_merge(acc[0][0][q], acc[1][0][q]);
            float xr = lo16(tv[q].x); if (DEC) xr += zr_[q];
            rg[q] = sigm2(xr + rm);
        }
        #pragma unroll
        for (int q=0;q<4;++q){
            float zm = permlane_merge(acc[0][1][q], acc[1][1][q]);
            float xz = hi16(tv[q].x); if (DEC) xz += zz_[q];
            zg[q] = sigm2(xz + zm);
        }
        #pragma unroll
        for (int q=0;q<4;++q){
            float nm = permlane_merge(acc[0][2][q], acc[1][2][q]);
            float xn = lo16(tv[q].y); if (DEC) xn += zn_[q];
            float ng = tanh2(__builtin_fmaf(rg[q], nm + bhn, xn));
            float hv = __builtin_fmaf(zg[q], hreg[q] - ng, ng);
            hreg[q] = hv;
            hbuf[(nxt<<12) + waddr[q]] = f2bf(hv);
        }
        __syncthreads();
        if (DEC){
            uint2 v = *(const uint2*)&hbuf[(nxt<<12) + csrc];
            *(uint2*)(cdst0 + (size_t)t*H_) = v;
        }
    };

    for (int t=0; t+1<Tn; t+=2){ step(t,0); step(t+1,1); }
    if (Tn & 1) step(Tn-1, 0);

#undef LDH
#undef MFMA_

    if (!DEC){
        #pragma unroll
        for (int q=0; q<4; ++q)
            h_last[(size_t)(b0+rbase+q)*H_ + col_m] = hreg[q];
    }
}

// ---------------- fused latent (mu/logvar/toq, KL, VQ, Q) + mid (hidden, zvp) ----------------
__global__ __launch_bounds__(256) void k_latmid(
    const float* __restrict__ hlast,
    const float* __restrict__ w_mu, const float* __restrict__ b_mu,
    const float* __restrict__ w_std, const float* __restrict__ b_std,
    const float* __restrict__ w_q, const float* __restrict__ b_q,
    const float* __restrict__ cb,
    const float* __restrict__ w_up, const float* __restrict__ b_up,
    const float* __restrict__ dwih,
    float* __restrict__ hidden, unsigned short* __restrict__ zvp,
    float* __restrict__ pKL, float* __restrict__ pQ, float* __restrict__ out_idx)
{
    __shared__ float hs[8][H_];
    __shared__ float mu8[8][Z_], lv8[8][Z_], tq8[8][Z_];
    __shared__ float cbs[256*Z_];
    __shared__ float red[256];
    __shared__ int redi[256];
    __shared__ float zs[8][64];
    const int tid = threadIdx.x;
    const int b0 = blockIdx.x*8;

    for (int i=tid; i<8*H_; i+=256) hs[i>>8][i&255] = hlast[(size_t)(b0+(i>>8))*H_ + (i&255)];
    __syncthreads();

    for (int id=tid; id<768; id+=256){
        int o = id % 96, bb = id / 96;
        int which = o>>5, zi = o&31;
        const float* wm = which==0 ? w_mu : (which==1 ? w_std : w_q);
        const float* bm = which==0 ? b_mu : (which==1 ? b_std : b_q);
        float s = bm[zi];
        const float* h = hs[bb];
        for (int k=0;k<H_;++k) s += h[k]*wm[zi*H_+k];
        if (which==0) mu8[bb][zi]=s; else if (which==1) lv8[bb][zi]=s; else tq8[bb][zi]=s;
    }
    __syncthreads();

    {
        int bb = tid>>5, zi = tid&31;
        float m = mu8[bb][zi], l = lv8[bb][zi];
        red[tid] = 0.5f*(m*m + __expf(l) - l - 1.0f);
    }
    __syncthreads();
    for (int s=128; s>0; s>>=1){ if (tid<s) red[tid]+=red[tid+s]; __syncthreads(); }
    if (tid==0) pKL[blockIdx.x] = red[0];
    __syncthreads();

    const int bb = tid>>5, c = tid&31;
    float best = 3.4e38f; int bi = 0;
    for (int ch=0; ch<4; ++ch){
        int kb = ch*256;
        int kn = (K_ - kb) < 256 ? (K_ - kb) : 256;
        for (int i=tid; i<kn*Z_; i+=256) cbs[i] = cb[(size_t)kb*Z_ + i];
        __syncthreads();
        for (int jj=0; jj<8; ++jj){
            int k = c + 32*(ch*8+jj);
            if (k < K_){
                const float* cv = &cbs[(k-kb)*Z_];
                float d = 0.f;
                #pragma unroll
                for (int ci=0; ci<Z_; ++ci){ float df = tq8[bb][ci]-cv[ci]; d += df*df; }
                if (d < best){ best = d; bi = k; }
            }
        }
        __syncthreads();
    }
    red[tid]=best; redi[tid]=bi;
    __syncthreads();
    for (int s=16; s>0; s>>=1){
        if ((tid&31) < s){
            float ob = red[tid+s]; int oi = redi[tid+s];
            if (ob < red[tid] || (ob == red[tid] && oi < redi[tid])){ red[tid]=ob; redi[tid]=oi; }
        }
        __syncthreads();
    }
    if (tid < 8){
        int k = redi[tid*32];
        float s = 0.f;
        for (int ci=0; ci<Z_; ++ci){ float df = cb[(size_t)k*Z_+ci]-tq8[tid][ci]; s += df*df; }
        red[tid] = s * (0.3f/32.0f);
        out_idx[b0+tid] = (float)k;
    }
    __syncthreads();
    if (tid==0){ float q=0; for (int i=0;i<8;++i) q+=red[i]; pQ[blockIdx.x]=q; }
    for (int i=tid; i<8*64; i+=256){
        int bb2 = i>>6, cc = i&63;
        int k = redi[bb2*32];
        zs[bb2][cc] = (cc < Z_) ? cb[(size_t)k*Z_+cc] : mu8[bb2][cc-Z_];
    }
    __syncthreads();

    // mid: hidden = zcat@w_up.T + b_up ; zvp = packed bf16 zcat@dec_wih[:, :64].T (r,z scaled)
    for (int id=tid; id<8*1024; id+=256){
        int bb2 = id>>10, o = id&1023;
        const float* zr = zs[bb2];
        if (o < H_){
            float s = b_up[o];
            const float* wr = w_up + o*64;
            for (int ck=0;ck<64;++ck) s += zr[ck]*wr[ck];
            hidden[(size_t)(b0+bb2)*H_ + o] = s;
        } else {
            int g = o - H_;
            int gate = g>>8, col = g&255;
            float s = 0.f;
            const float* wr = dwih + (size_t)g*128;
            for (int ck=0;ck<64;++ck) s += zr[ck]*wr[ck];
            if (gate < 2) s *= LOG2E;
            zvp[((size_t)(b0+bb2)*256 + col)*4 + gate] = f2bf(s);
        }
    }
}

// ---------------- logits + log_softmax + loss ----------------
__global__ __launch_bounds__(256) void k_loss(
    const unsigned short* __restrict__ outs, const unsigned short* __restrict__ bpo,
    const float* __restrict__ b_out, const int* __restrict__ x,
    float* __restrict__ pred, float* __restrict__ pXL, float* __restrict__ pNP)
{
    __shared__ float ll[16][64];
    __shared__ float bo[64];
    __shared__ float redf[256], redn[256];
    const int tid = threadIdx.x, w = tid>>6, lane = tid&63, lr = lane&15, lp = lane>>4;
    const bf16x8* bpofr = (const bf16x8*)bpo;
    bf16x8 bw[8];
    #pragma unroll
    for (int kt=0;kt<8;++kt) bw[kt] = bpofr[(w*8+kt)*64 + lane];
    if (tid < 64) bo[tid] = (tid < V_) ? b_out[tid] : 0.0f;
    float xl = 0.f, npn = 0.f;
    const int row = tid>>4, vl = tid&15;
    for (int cc=0; cc<4; ++cc){
        int row0 = (blockIdx.x*4 + cc)*16;
        floatx4 acc = {0,0,0,0};
        #pragma unroll
        for (int kt=0;kt<8;++kt){
            bf16x8 av = *(const bf16x8*)&outs[(size_t)(row0+lr)*H_ + kt*32 + lp*8];
            acc = __builtin_amdgcn_mfma_f32_16x16x32_bf16(av, bw[kt], acc, 0,0,0);
        }
        __syncthreads();
        #pragma unroll
        for (int q=0;q<4;++q) ll[lp*4+q][w*16+lr] = acc[q];
        __syncthreads();
        float lv[4];
        #pragma unroll
        for (int k2=0;k2<4;++k2){
            int v = vl + 16*k2;
            lv[k2] = (v < V_) ? ll[row][v] + bo[v] : -3.4e38f;
        }
        float m = lv[0]; int am = vl;
        #pragma unroll
        for (int k2=1;k2<4;++k2){ if (lv[k2] > m){ m = lv[k2]; am = vl + 16*k2; } }
        #pragma unroll
        for (int off=1; off<16; off<<=1){
            float om = __shfl_xor(m, off, 16);
            int oa = __shfl_xor(am, off, 16);
            if (om > m || (om == m && oa < am)){ m = om; am = oa; }
        }
        float se = 0.f;
        #pragma unroll
        for (int k2=0;k2<4;++k2) se += __expf(lv[k2]-m);
        #pragma unroll
        for (int off=1; off<16; off<<=1) se += __shfl_xor(se, off, 16);
        if (vl == 0){
            int rowg = row0 + row;
            int b = rowg/63, tt = rowg - b*63;
            int tgt = x[(size_t)b*T_ + tt + 1];
            pred[rowg] = (float)am;
            if (tgt != 0){
                float lse = m + __logf(se);
                xl += ll[row][tgt] + bo[tgt] - lse;
                npn += 1.f;
            }
        }
    }
    redf[tid]=xl; redn[tid]=npn;
    __syncthreads();
    for (int s=128;s>0;s>>=1){ if (tid<s){ redf[tid]+=redf[tid+s]; redn[tid]+=redn[tid+s]; } __syncthreads(); }
    if (tid==0){ pXL[blockIdx.x]=redf[0]; pNP[blockIdx.x]=redn[0]; }
}

// ---------------- final reduce ----------------
__global__ __launch_bounds__(256) void k_reduce(
    const float* __restrict__ pKL, const float* __restrict__ pQ,
    const float* __restrict__ pXL, const float* __restrict__ pNP, float* __restrict__ dout)
{
    __shared__ float r[256];
    const int tid = threadIdx.x;
    r[tid] = pKL[tid]; __syncthreads();
    for (int s=128;s>0;s>>=1){ if (tid<s) r[tid]+=r[tid+s]; __syncthreads(); }
    if (tid==0) dout[129026] = r[0];
    __syncthreads();
    r[tid] = pQ[tid]; __syncthreads();
    for (int s=128;s>0;s>>=1){ if (tid<s) r[tid]+=r[tid+s]; __syncthreads(); }
    if (tid==0) dout[129027] = r[0];
    __syncthreads();
    float a = 0.f;
    for (int i=tid;i<2016;i+=256) a += pXL[i];
    r[tid] = a; __syncthreads();
    for (int s=128;s>0;s>>=1){ if (tid<s) r[tid]+=r[tid+s]; __syncthreads(); }
    if (tid==0) dout[0] = -r[0];
    __syncthreads();
    a = 0.f;
    for (int i=tid;i<2016;i+=256) a += pNP[i];
    r[tid] = a; __syncthreads();
    for (int s=128;s>0;s>>=1){ if (tid<s) r[tid]+=r[tid+s]; __syncthreads(); }
    if (tid==0) dout[1] = r[0];
}

extern "C" void kernel_launch(void* const* d_in, const int* in_sizes, int n_in,
                              void* d_out, int out_size, void* d_ws, size_t ws_size,
                              hipStream_t stream)
{
    const int*   x       = (const int*)  d_in[0];
    const float* enc_emb = (const float*)d_in[1];
    const float* enc_wih = (const float*)d_in[2];
    const float* enc_whh = (const float*)d_in[3];
    const float* enc_bih = (const float*)d_in[4];
    const float* enc_bhh = (const float*)d_in[5];
    const float* w_mu    = (const float*)d_in[6];
    const float* b_mu    = (const float*)d_in[7];
    const float* w_std   = (const float*)d_in[8];
    const float* b_std   = (const float*)d_in[9];
    const float* w_q     = (const float*)d_in[10];
    const float* b_q     = (const float*)d_in[11];
    const float* w_up    = (const float*)d_in[12];
    const float* b_up    = (const float*)d_in[13];
    const float* cb      = (const float*)d_in[14];
    const float* dec_emb = (const float*)d_in[15];
    const float* dec_wih = (const float*)d_in[16];
    const float* dec_whh = (const float*)d_in[17];
    const float* dec_bih = (const float*)d_in[18];
    const float* dec_bhh = (const float*)d_in[19];
    const float* w_out   = (const float*)d_in[20];
    const float* b_out   = (const float*)d_in[21];

    float* ws = (float*)d_ws;
    unsigned short* tep = (unsigned short*)(ws + 0);        // 52224 ush
    unsigned short* tdp = (unsigned short*)(ws + 26112);    // 52224 ush
    unsigned short* bpe = (unsigned short*)(ws + 52224);    // 196608 ush
    unsigned short* bpd = (unsigned short*)(ws + 150528);   // 196608 ush
    unsigned short* bpo = (unsigned short*)(ws + 248832);   // 16384 ush
    float* hl   = ws + 257024;    // 524288
    float* hid  = ws + 912384;    // 524288
    unsigned short* zvp  = (unsigned short*)(ws + 1436672); // 2097152 ush
    unsigned short* outs = (unsigned short*)(ws + 2485248); // 33030144 ush
    float* pKL  = ws + 19000320;  // 256
    float* pQ   = ws + 19000576;  // 256
    float* pXL  = ws + 19000832;  // 2016
    float* pNP  = ws + 19002848;  // 2016

    float* dout = (float*)d_out;

    k_prep<<<1906,256,0,stream>>>(enc_emb, enc_wih, enc_bih, enc_bhh,
                                  dec_emb, dec_wih, dec_bih, dec_bhh,
                                  enc_whh, dec_whh, w_out,
                                  tep, tdp, bpe, bpd, bpo);
    k_gru<0><<<256,512,0,stream>>>(x, tep, bpe, enc_bhh, nullptr, nullptr, hl, nullptr);
    k_latmid<<<256,256,0,stream>>>(hl, w_mu,b_mu,w_std,b_std,w_q,b_q, cb,
                                   w_up, b_up, dec_wih, hid, zvp, pKL, pQ, dout + 129028);
    k_gru<1><<<256,512,0,stream>>>(x, tdp, bpd, dec_bhh, hid, zvp, nullptr, outs);
    k_loss<<<2016,256,0,stream>>>(outs, bpo, b_out, x, dout + 2, pXL, pNP);
    k_reduce<<<1,256,0,stream>>>(pKL, pQ, pXL, pNP, dout);
}